// Round 2
// baseline (97.388 us; speedup 1.0000x reference)
//
#include <hip/hip_runtime.h>

#define NOUT1 12
#define NOUT2 15
#define NBINS 4000
#define NFEAT 6
#define NT    500
#define NEVT  64

__device__ __forceinline__ float leaky(float s) {
    return s >= 0.0f ? s : 0.01f * s;
}

// softplus(x) = log1p(exp(x)) = max(x,0) + ln2 * log2(1 + 2^(-|x|*log2e))
__device__ __forceinline__ float softplus(float x) {
    float e = __builtin_amdgcn_exp2f(fabsf(x) * -1.4426950408889634f);
    float l = __builtin_amdgcn_logf(1.0f + e);   // log2
    return fmaf(0.6931471805599453f, l, fmaxf(x, 0.0f));
}

__global__ __launch_bounds__(256, 2) void tracks_kde_kernel(
    const float* __restrict__ x,
    const float* __restrict__ W1, const float* __restrict__ b1,
    const float* __restrict__ W2, const float* __restrict__ b2,
    const float* __restrict__ W3, const float* __restrict__ b3,
    float* __restrict__ out)
{
    // h2 for this block's event, padded to 16 floats/row for aligned float4 reads
    __shared__ float h2s[NT][16];

    const int tid   = threadIdx.x;
    const int chunk = blockIdx.x;   // 0..7  -> bin chunk of 512
    const int e     = blockIdx.y;   // 0..63 -> event

    // ---- Phase 1: compute h2[e, t, :] into LDS (cheap: ~250 ops per t) ----
    for (int t = tid; t < NT; t += 256) {
        float f[NFEAT];
        #pragma unroll
        for (int i = 0; i < NFEAT; ++i)
            f[i] = x[e * NFEAT * NT + i * NT + t];   // x is (E, F, T)

        float h1[NOUT1];
        #pragma unroll
        for (int o = 0; o < NOUT1; ++o) {
            float s = b1[o];
            #pragma unroll
            for (int i = 0; i < NFEAT; ++i)
                s = fmaf(f[i], W1[o * NFEAT + i], s);
            h1[o] = leaky(s);
        }
        #pragma unroll
        for (int o = 0; o < NOUT2; ++o) {
            float s = b2[o];
            #pragma unroll
            for (int i = 0; i < NOUT1; ++i)
                s = fmaf(h1[i], W2[o * NOUT1 + i], s);
            h2s[t][o] = leaky(s);
        }
        h2s[t][15] = 0.0f;
    }
    __syncthreads();

    // ---- Phase 2: each thread owns 2 output bins; loop over 500 tracks ----
    const int o0 = chunk * 512 + tid;
    const int o1 = o0 + 256;
    const bool v0 = (o0 < NBINS);
    const bool v1 = (o1 < NBINS);

    float w0[NOUT2], w1[NOUT2];
    #pragma unroll
    for (int k = 0; k < NOUT2; ++k) {
        w0[k] = v0 ? W3[o0 * NOUT2 + k] : 0.0f;
        w1[k] = v1 ? W3[o1 * NOUT2 + k] : 0.0f;
    }
    const float bb0 = v0 ? b3[o0] : 0.0f;
    const float bb1 = v1 ? b3[o1] : 0.0f;

    float acc0 = 0.0f, acc1 = 0.0f;

    #pragma unroll 2
    for (int t = 0; t < NT; ++t) {
        // wave-uniform address -> LDS broadcast, no bank conflicts
        const float4* hp = reinterpret_cast<const float4*>(&h2s[t][0]);
        float4 ha = hp[0], hb = hp[1], hc = hp[2], hd = hp[3];
        float h[16] = {ha.x, ha.y, ha.z, ha.w,
                       hb.x, hb.y, hb.z, hb.w,
                       hc.x, hc.y, hc.z, hc.w,
                       hd.x, hd.y, hd.z, hd.w};

        float d0 = bb0, d1 = bb1;
        #pragma unroll
        for (int k = 0; k < NOUT2; ++k) {
            d0 = fmaf(h[k], w0[k], d0);
            d1 = fmaf(h[k], w1[k], d1);
        }
        acc0 += softplus(d0);
        acc1 += softplus(d1);
    }

    if (v0) out[e * NBINS + o0] = acc0;
    if (v1) out[e * NBINS + o1] = acc1;
}

extern "C" void kernel_launch(void* const* d_in, const int* in_sizes, int n_in,
                              void* d_out, int out_size, void* d_ws, size_t ws_size,
                              hipStream_t stream) {
    const float* x  = (const float*)d_in[0];
    const float* W1 = (const float*)d_in[1];
    const float* b1 = (const float*)d_in[2];
    const float* W2 = (const float*)d_in[3];
    const float* b2 = (const float*)d_in[4];
    const float* W3 = (const float*)d_in[5];
    const float* b3 = (const float*)d_in[6];
    float* out = (float*)d_out;

    dim3 grid(8, NEVT);   // 8 bin-chunks of 512, 64 events
    tracks_kde_kernel<<<grid, 256, 0, stream>>>(x, W1, b1, W2, b2, W3, b3, out);
}

// Round 3
// 91.488 us; speedup vs baseline: 1.0645x; 1.0645x over previous
//
#include <hip/hip_runtime.h>

#define NOUT1 12
#define NOUT2 15
#define NBINS 4000
#define NFEAT 6
#define NT    500
#define NEVT  64
#define THALF 250   // tracks per block (NT split in 2)

__device__ __forceinline__ float leaky(float s) {
    return s >= 0.0f ? s : 0.01f * s;
}

// softplus(x) = max(x,0) + ln(1+u), u = 2^(-|x|*log2e) in (0,1]
// ln(1+u) ~= u*(c1 + u*(c2 + u*c3)), minimax cubic, |abs err| <= ~8e-4
__device__ __forceinline__ float softplus_fast(float x) {
    float u = __builtin_amdgcn_exp2f(fabsf(x) * -1.4426950408889634f);
    float q = fmaf(u, fmaf(u, 0.121416f, -0.417801f), 0.990311f);
    return fmaf(u, q, fmaxf(x, 0.0f));
}

__global__ __launch_bounds__(256, 4) void tracks_kde_kernel(
    const float* __restrict__ x,
    const float* __restrict__ W1, const float* __restrict__ b1,
    const float* __restrict__ W2, const float* __restrict__ b2,
    const float* __restrict__ W3, const float* __restrict__ b3,
    float* __restrict__ out)
{
    // h2 for this block's track-half, padded to 16 floats/row (aligned float4)
    __shared__ float h2s[THALF][16];

    const int tid   = threadIdx.x;
    const int chunk = blockIdx.x;   // 0..7  -> bin chunk of 512
    const int e     = blockIdx.y;   // 0..63 -> event
    const int half  = blockIdx.z;   // 0..1  -> track half

    // ---- Phase 1: compute h2 for 250 tracks (one per thread) ----
    if (tid < THALF) {
        const int t = tid;
        const int g = half * THALF + t;   // global track index

        float f[NFEAT];
        #pragma unroll
        for (int i = 0; i < NFEAT; ++i)
            f[i] = x[e * NFEAT * NT + i * NT + g];   // x is (E, F, T)

        float h1[NOUT1];
        #pragma unroll
        for (int o = 0; o < NOUT1; ++o) {
            float s = b1[o];
            #pragma unroll
            for (int i = 0; i < NFEAT; ++i)
                s = fmaf(f[i], W1[o * NFEAT + i], s);
            h1[o] = leaky(s);
        }
        #pragma unroll
        for (int o = 0; o < NOUT2; ++o) {
            float s = b2[o];
            #pragma unroll
            for (int i = 0; i < NOUT1; ++i)
                s = fmaf(h1[i], W2[o * NOUT1 + i], s);
            h2s[t][o] = leaky(s);
        }
        h2s[t][15] = 0.0f;
    }
    __syncthreads();

    // ---- Phase 2: each thread owns 2 bins; loop over 250 tracks ----
    const int o0 = chunk * 512 + tid;
    const int o1 = o0 + 256;
    const bool v0 = (o0 < NBINS);
    const bool v1 = (o1 < NBINS);

    float w0[NOUT2], w1[NOUT2];
    #pragma unroll
    for (int k = 0; k < NOUT2; ++k) {
        w0[k] = v0 ? W3[o0 * NOUT2 + k] : 0.0f;
        w1[k] = v1 ? W3[o1 * NOUT2 + k] : 0.0f;
    }
    const float bb0 = v0 ? b3[o0] : 0.0f;
    const float bb1 = v1 ? b3[o1] : 0.0f;

    float acc0 = 0.0f, acc1 = 0.0f;

    #pragma unroll 2
    for (int t = 0; t < THALF; ++t) {
        // wave-uniform address -> LDS broadcast, conflict-free
        const float4* hp = reinterpret_cast<const float4*>(&h2s[t][0]);
        float4 ha = hp[0], hb = hp[1], hc = hp[2], hd = hp[3];
        float h[16] = {ha.x, ha.y, ha.z, ha.w,
                       hb.x, hb.y, hb.z, hb.w,
                       hc.x, hc.y, hc.z, hc.w,
                       hd.x, hd.y, hd.z, hd.w};

        // 4 independent FMA chains (2 bins x 2 partials)
        float d0a = bb0, d0b = 0.0f, d1a = bb1, d1b = 0.0f;
        #pragma unroll
        for (int k = 0; k < 8; ++k) {
            d0a = fmaf(h[k], w0[k], d0a);
            d1a = fmaf(h[k], w1[k], d1a);
        }
        #pragma unroll
        for (int k = 8; k < NOUT2; ++k) {
            d0b = fmaf(h[k], w0[k], d0b);
            d1b = fmaf(h[k], w1[k], d1b);
        }
        acc0 += softplus_fast(d0a + d0b);
        acc1 += softplus_fast(d1a + d1b);
    }

    // exactly 2 contributors per address (track halves); fp32 add is
    // commutative -> bit-deterministic result
    if (v0) atomicAdd(&out[e * NBINS + o0], acc0);
    if (v1) atomicAdd(&out[e * NBINS + o1], acc1);
}

extern "C" void kernel_launch(void* const* d_in, const int* in_sizes, int n_in,
                              void* d_out, int out_size, void* d_ws, size_t ws_size,
                              hipStream_t stream) {
    const float* x  = (const float*)d_in[0];
    const float* W1 = (const float*)d_in[1];
    const float* b1 = (const float*)d_in[2];
    const float* W2 = (const float*)d_in[3];
    const float* b2 = (const float*)d_in[4];
    const float* W3 = (const float*)d_in[5];
    const float* b3 = (const float*)d_in[6];
    float* out = (float*)d_out;

    hipMemsetAsync(d_out, 0, (size_t)out_size * sizeof(float), stream);

    dim3 grid(8, NEVT, 2);   // 8 bin-chunks x 64 events x 2 track-halves
    tracks_kde_kernel<<<grid, 256, 0, stream>>>(x, W1, b1, W2, b2, W3, b3, out);
}

// Round 4
// 48.757 us; speedup vs baseline: 1.9974x; 1.8764x over previous
//
#include <hip/hip_runtime.h>

#define NOUT1 12
#define NOUT2 15
#define NBINS 4000
#define NFEAT 6
#define NT    500
#define NTPAD 512
#define NEVT  64
#define ROWB  80   // LDS row stride bytes: 32 bf16 (64B) + 16B pad -> conflict-free ds_read_b128

typedef __attribute__((ext_vector_type(8))) short bf16x8;
typedef __attribute__((ext_vector_type(4))) float f32x4;

__device__ __forceinline__ float leaky(float s) {
    return s >= 0.0f ? s : 0.01f * s;
}

// softplus(x) = max(x,0) + ln(1+u), u = exp(-|x|); cubic minimax for ln(1+u)
__device__ __forceinline__ float softplus_fast(float x) {
    float u = __builtin_amdgcn_exp2f(fabsf(x) * -1.4426950408889634f);
    float q = fmaf(u, fmaf(u, 0.121416f, -0.417801f), 0.990311f);
    return fmaf(u, q, fmaxf(x, 0.0f));
}

__device__ __forceinline__ unsigned short f32_to_bf16_rne(float x) {
    unsigned int u = __float_as_uint(x);
    unsigned int r = (u + 0x7fffu + ((u >> 16) & 1u)) >> 16;
    return (unsigned short)r;
}
__device__ __forceinline__ float bf16_to_f32(unsigned short h) {
    return __uint_as_float((unsigned int)h << 16);
}

__global__ __launch_bounds__(1024, 8) void tracks_kde_mfma(
    const float* __restrict__ x,
    const float* __restrict__ W1, const float* __restrict__ b1,
    const float* __restrict__ W2, const float* __restrict__ b2,
    const float* __restrict__ W3, const float* __restrict__ b3,
    float* __restrict__ out)
{
    // h2 split rows: slot s in [0,32): s<16 -> hi[s] (s==15 pad 0), s>=16 -> lo[s-16]
    __shared__ __align__(16) unsigned char h2lds[NTPAD * ROWB];

    const int tid   = threadIdx.x;
    const int chunk = blockIdx.x;   // 0..15 -> 256 bins each
    const int e     = blockIdx.y;   // 0..63

    // ---- Phase 1: one padded track per thread (tid 0..511) ----
    if (tid < NTPAD) {
        const int t = tid;
        unsigned int packed[16];
        if (t < NT) {
            float f[NFEAT];
            #pragma unroll
            for (int i = 0; i < NFEAT; ++i)
                f[i] = x[e * NFEAT * NT + i * NT + t];   // x is (E, F, T)

            float h1[NOUT1];
            #pragma unroll
            for (int o = 0; o < NOUT1; ++o) {
                float s = b1[o];
                #pragma unroll
                for (int i = 0; i < NFEAT; ++i)
                    s = fmaf(f[i], W1[o * NFEAT + i], s);
                h1[o] = leaky(s);
            }

            unsigned short hi[16], lo[16];
            #pragma unroll
            for (int o = 0; o < NOUT2; ++o) {
                float s = b2[o];
                #pragma unroll
                for (int i = 0; i < NOUT1; ++i)
                    s = fmaf(h1[i], W2[o * NOUT1 + i], s);
                float h2 = leaky(s);
                unsigned short hh = f32_to_bf16_rne(h2);
                hi[o] = hh;
                lo[o] = f32_to_bf16_rne(h2 - bf16_to_f32(hh));
            }
            hi[15] = 0; lo[15] = 0;
            #pragma unroll
            for (int j = 0; j < 8; ++j) {
                packed[j]     = (unsigned int)hi[2*j] | ((unsigned int)hi[2*j+1] << 16);
                packed[8 + j] = (unsigned int)lo[2*j] | ((unsigned int)lo[2*j+1] << 16);
            }
        } else {
            #pragma unroll
            for (int j = 0; j < 16; ++j) packed[j] = 0;
        }
        uint4* row = reinterpret_cast<uint4*>(&h2lds[t * ROWB]);
        #pragma unroll
        for (int g = 0; g < 4; ++g)
            row[g] = make_uint4(packed[4*g+0], packed[4*g+1], packed[4*g+2], packed[4*g+3]);
    }
    __syncthreads();

    // ---- Phase 2: wave = 16 bins x all tracks via MFMA ----
    const int wid  = tid >> 6;    // 0..15
    const int lane = tid & 63;
    const int col  = lane & 15;   // bin within tile; also A-row supplied by this lane
    const int kg   = lane >> 4;   // k-group 0..3 (8 k-slots each)
    const int binbase = chunk * 256 + wid * 16;
    if (binbase >= NBINS) return;              // wave-uniform; no barriers after this
    const int  bin = binbase + col;
    const bool vb  = (bin < NBINS);

    // B fragments: B1 k-slots = [w_hi | w_lo], B2 = halves swapped.
    // lane supplies B[k = kg*8+j][col]; kk = k & 15 indexes W3 row.
    bf16x8 B1, B2;
    const bool hi_first = (kg < 2);
    #pragma unroll
    for (int j = 0; j < 8; ++j) {
        const int kk = (kg * 8 + j) & 15;
        float w = (vb && kk < NOUT2) ? W3[bin * NOUT2 + kk] : 0.0f;
        unsigned short h = f32_to_bf16_rne(w);
        unsigned short l = f32_to_bf16_rne(w - bf16_to_f32(h));
        B1[j] = (short)(hi_first ? h : l);
        B2[j] = (short)(hi_first ? l : h);
    }

    const float bias = vb ? b3[bin] : 0.0f;
    f32x4 bias4 = {bias, bias, bias, bias};

    float sum = 0.0f;
    const unsigned char* abase = &h2lds[col * ROWB + kg * 16];

    // MFMA1: hh*wh + hl*wl ; MFMA2: hh*wl + hl*wh  => exact (h_hi+h_lo)(w_hi+w_lo)
    #pragma unroll 2
    for (int tt = 0; tt < 31; ++tt) {
        bf16x8 a = *reinterpret_cast<const bf16x8*>(abase + tt * 16 * ROWB);
        f32x4 acc = __builtin_amdgcn_mfma_f32_16x16x32_bf16(a, B1, bias4, 0, 0, 0);
        acc = __builtin_amdgcn_mfma_f32_16x16x32_bf16(a, B2, acc, 0, 0, 0);
        sum += softplus_fast(acc[0]);
        sum += softplus_fast(acc[1]);
        sum += softplus_fast(acc[2]);
        sum += softplus_fast(acc[3]);
    }
    {   // last tile: tracks 496..511; C row = kg*4+r -> only kg==0 rows (<500) are real
        bf16x8 a = *reinterpret_cast<const bf16x8*>(abase + 31 * 16 * ROWB);
        f32x4 acc = __builtin_amdgcn_mfma_f32_16x16x32_bf16(a, B1, bias4, 0, 0, 0);
        acc = __builtin_amdgcn_mfma_f32_16x16x32_bf16(a, B2, acc, 0, 0, 0);
        if (kg == 0) {
            sum += softplus_fast(acc[0]);
            sum += softplus_fast(acc[1]);
            sum += softplus_fast(acc[2]);
            sum += softplus_fast(acc[3]);
        }
    }

    // combine the 4 row-groups holding the same bin: lanes c, c+16, c+32, c+48
    sum += __shfl_xor(sum, 16);
    sum += __shfl_xor(sum, 32);
    if (lane < 16 && vb)
        out[e * NBINS + bin] = sum;
}

extern "C" void kernel_launch(void* const* d_in, const int* in_sizes, int n_in,
                              void* d_out, int out_size, void* d_ws, size_t ws_size,
                              hipStream_t stream) {
    const float* x  = (const float*)d_in[0];
    const float* W1 = (const float*)d_in[1];
    const float* b1 = (const float*)d_in[2];
    const float* W2 = (const float*)d_in[3];
    const float* b2 = (const float*)d_in[4];
    const float* W3 = (const float*)d_in[5];
    const float* b3 = (const float*)d_in[6];
    float* out = (float*)d_out;

    dim3 grid(16, NEVT);   // 16 bin-chunks of 256 x 64 events
    tracks_kde_mfma<<<grid, 1024, 0, stream>>>(x, W1, b1, W2, b2, W3, b3, out);
}

// Round 5
// 48.672 us; speedup vs baseline: 2.0009x; 1.0018x over previous
//
#include <hip/hip_runtime.h>

#define NOUT1 12
#define NOUT2 15
#define NBINS 4000
#define NFEAT 6
#define NT    500
#define NTPAD 512
#define NEVT  64
#define ROWB  80   // LDS row stride bytes: 32 bf16 (64B) + 16B pad

typedef __attribute__((ext_vector_type(8))) short bf16x8;
typedef __attribute__((ext_vector_type(4))) float f32x4;
typedef __attribute__((ext_vector_type(2))) float f32x2;

__device__ __forceinline__ float leaky(float s) {
    return s >= 0.0f ? s : 0.01f * s;
}

__device__ __forceinline__ unsigned short f32_to_bf16_rne(float x) {
    unsigned int u = __float_as_uint(x);
    unsigned int r = (u + 0x7fffu + ((u >> 16) & 1u)) >> 16;
    return (unsigned short)r;
}
__device__ __forceinline__ float bf16_to_f32(unsigned short h) {
    return __uint_as_float((unsigned int)h << 16);
}

// packed softplus: per pair, v_pk_{max,min,mul,fma*3,add} + 2x v_exp
// softplus(x) = max(x,0) + ln(1+u), u = exp(-|x|); cubic minimax, |err|<=8e-4
__device__ __forceinline__ f32x2 softplus2(f32x2 p) {
    f32x2 m = __builtin_elementwise_max(p, (f32x2)0.0f);
    f32x2 n = __builtin_elementwise_min(p, -p);            // -|x|
    f32x2 a = n * (f32x2)1.4426950408889634f;
    f32x2 u;
    u.x = __builtin_amdgcn_exp2f(a.x);
    u.y = __builtin_amdgcn_exp2f(a.y);
    f32x2 q = __builtin_elementwise_fma(u, (f32x2)0.121416f, (f32x2)(-0.417801f));
    q = __builtin_elementwise_fma(u, q, (f32x2)0.990311f);
    return __builtin_elementwise_fma(u, q, m);
}

// ---- compute one track's h2 hi/lo bf16 row (16 packed uints) ----
__device__ __forceinline__ void h2_row(
    const float* __restrict__ x, int e, int t,
    const float* __restrict__ W1, const float* __restrict__ b1,
    const float* __restrict__ W2, const float* __restrict__ b2,
    unsigned int packed[16])
{
    float f[NFEAT];
    #pragma unroll
    for (int i = 0; i < NFEAT; ++i)
        f[i] = x[e * NFEAT * NT + i * NT + t];   // x is (E, F, T)

    float h1[NOUT1];
    #pragma unroll
    for (int o = 0; o < NOUT1; ++o) {
        float s = b1[o];
        #pragma unroll
        for (int i = 0; i < NFEAT; ++i)
            s = fmaf(f[i], W1[o * NFEAT + i], s);
        h1[o] = leaky(s);
    }

    unsigned short hi[16], lo[16];
    #pragma unroll
    for (int o = 0; o < NOUT2; ++o) {
        float s = b2[o];
        #pragma unroll
        for (int i = 0; i < NOUT1; ++i)
            s = fmaf(h1[i], W2[o * NOUT1 + i], s);
        float h2 = leaky(s);
        unsigned short hh = f32_to_bf16_rne(h2);
        hi[o] = hh;
        lo[o] = f32_to_bf16_rne(h2 - bf16_to_f32(hh));
    }
    hi[15] = 0; lo[15] = 0;
    #pragma unroll
    for (int j = 0; j < 8; ++j) {
        packed[j]     = (unsigned int)hi[2*j] | ((unsigned int)hi[2*j+1] << 16);
        packed[8 + j] = (unsigned int)lo[2*j] | ((unsigned int)lo[2*j+1] << 16);
    }
}

// ---- Kernel 1: h2 prep, once per (event, track) -> d_ws ----
__global__ __launch_bounds__(512) void h2_prep(
    const float* __restrict__ x,
    const float* __restrict__ W1, const float* __restrict__ b1,
    const float* __restrict__ W2, const float* __restrict__ b2,
    uint4* __restrict__ ws)
{
    const int e = blockIdx.x;
    const int t = threadIdx.x;
    unsigned int packed[16];
    if (t < NT) {
        h2_row(x, e, t, W1, b1, W2, b2, packed);
    } else {
        #pragma unroll
        for (int j = 0; j < 16; ++j) packed[j] = 0;
    }
    uint4* row = ws + ((size_t)e * NTPAD + t) * 4;
    #pragma unroll
    for (int g = 0; g < 4; ++g)
        row[g] = make_uint4(packed[4*g+0], packed[4*g+1], packed[4*g+2], packed[4*g+3]);
}

// ---- Phase 2 body (shared by both variants) ----
__device__ __forceinline__ void kde_phase2(
    const unsigned char* __restrict__ h2lds,
    const float* __restrict__ W3, const float* __restrict__ b3,
    float* __restrict__ out, int chunk, int e, int tid)
{
    const int wid  = tid >> 6;    // 0..15
    const int lane = tid & 63;
    const int col  = lane & 15;   // bin within tile; also A-row supplied by this lane
    const int kg   = lane >> 4;   // k-group 0..3
    const int binbase = chunk * 256 + wid * 16;
    if (binbase >= NBINS) return;              // wave-uniform
    const int  bin = binbase + col;
    const bool vb  = (bin < NBINS);

    // B fragments: B1 k-slots = [w_hi | w_lo], B2 = halves swapped
    bf16x8 B1, B2;
    const bool hi_first = (kg < 2);
    #pragma unroll
    for (int j = 0; j < 8; ++j) {
        const int kk = (kg * 8 + j) & 15;
        float w = (vb && kk < NOUT2) ? W3[bin * NOUT2 + kk] : 0.0f;
        unsigned short h = f32_to_bf16_rne(w);
        unsigned short l = f32_to_bf16_rne(w - bf16_to_f32(h));
        B1[j] = (short)(hi_first ? h : l);
        B2[j] = (short)(hi_first ? l : h);
    }

    const float bias = vb ? b3[bin] : 0.0f;
    f32x4 bias4 = {bias, bias, bias, bias};

    f32x2 acc01 = {0.0f, 0.0f}, acc23 = {0.0f, 0.0f};
    const unsigned char* abase = &h2lds[col * ROWB + kg * 16];

    // MFMA1: hh*wh + hl*wl ; MFMA2: hh*wl + hl*wh => exact split product
    #pragma unroll
    for (int tt = 0; tt < 31; ++tt) {
        bf16x8 a = *reinterpret_cast<const bf16x8*>(abase + tt * 16 * ROWB);
        f32x4 acc = __builtin_amdgcn_mfma_f32_16x16x32_bf16(a, B1, bias4, 0, 0, 0);
        acc = __builtin_amdgcn_mfma_f32_16x16x32_bf16(a, B2, acc, 0, 0, 0);
        f32x2 p01 = {acc[0], acc[1]};
        f32x2 p23 = {acc[2], acc[3]};
        acc01 += softplus2(p01);
        acc23 += softplus2(p23);
    }
    {   // last tile: tracks 496..511; only kg==0 rows (<500) are real
        bf16x8 a = *reinterpret_cast<const bf16x8*>(abase + 31 * 16 * ROWB);
        f32x4 acc = __builtin_amdgcn_mfma_f32_16x16x32_bf16(a, B1, bias4, 0, 0, 0);
        acc = __builtin_amdgcn_mfma_f32_16x16x32_bf16(a, B2, acc, 0, 0, 0);
        if (kg == 0) {
            f32x2 p01 = {acc[0], acc[1]};
            f32x2 p23 = {acc[2], acc[3]};
            acc01 += softplus2(p01);
            acc23 += softplus2(p23);
        }
    }

    float sum = acc01.x + acc01.y + acc23.x + acc23.y;
    sum += __shfl_xor(sum, 16);
    sum += __shfl_xor(sum, 32);
    if (lane < 16 && vb)
        out[e * NBINS + bin] = sum;
}

// ---- Kernel 2: load h2 from ws, MFMA + softplus ----
__global__ __launch_bounds__(1024, 2) void kde_main(
    const uint4* __restrict__ ws,
    const float* __restrict__ W3, const float* __restrict__ b3,
    float* __restrict__ out)
{
    __shared__ __align__(16) unsigned char h2lds[NTPAD * ROWB];
    const int tid   = threadIdx.x;
    const int chunk = blockIdx.x;
    const int e     = blockIdx.y;

    #pragma unroll
    for (int it = 0; it < 2; ++it) {
        const int i = tid + it * 1024;          // 0..2047 -> uint4 index
        uint4 v = ws[(size_t)e * (NTPAD * 4) + i];
        const int t = i >> 2, g = i & 3;
        *reinterpret_cast<uint4*>(&h2lds[t * ROWB + g * 16]) = v;
    }
    __syncthreads();

    kde_phase2(h2lds, W3, b3, out, chunk, e, tid);
}

// ---- Fallback: fused single kernel (if ws too small) ----
__global__ __launch_bounds__(1024, 2) void kde_fused(
    const float* __restrict__ x,
    const float* __restrict__ W1, const float* __restrict__ b1,
    const float* __restrict__ W2, const float* __restrict__ b2,
    const float* __restrict__ W3, const float* __restrict__ b3,
    float* __restrict__ out)
{
    __shared__ __align__(16) unsigned char h2lds[NTPAD * ROWB];
    const int tid   = threadIdx.x;
    const int chunk = blockIdx.x;
    const int e     = blockIdx.y;

    if (tid < NTPAD) {
        unsigned int packed[16];
        if (tid < NT) {
            h2_row(x, e, tid, W1, b1, W2, b2, packed);
        } else {
            #pragma unroll
            for (int j = 0; j < 16; ++j) packed[j] = 0;
        }
        uint4* row = reinterpret_cast<uint4*>(&h2lds[tid * ROWB]);
        #pragma unroll
        for (int g = 0; g < 4; ++g)
            row[g] = make_uint4(packed[4*g+0], packed[4*g+1], packed[4*g+2], packed[4*g+3]);
    }
    __syncthreads();

    kde_phase2(h2lds, W3, b3, out, chunk, e, tid);
}

extern "C" void kernel_launch(void* const* d_in, const int* in_sizes, int n_in,
                              void* d_out, int out_size, void* d_ws, size_t ws_size,
                              hipStream_t stream) {
    const float* x  = (const float*)d_in[0];
    const float* W1 = (const float*)d_in[1];
    const float* b1 = (const float*)d_in[2];
    const float* W2 = (const float*)d_in[3];
    const float* b2 = (const float*)d_in[4];
    const float* W3 = (const float*)d_in[5];
    const float* b3 = (const float*)d_in[6];
    float* out = (float*)d_out;

    const size_t ws_needed = (size_t)NEVT * NTPAD * 64;   // 2 MB of packed h2
    if (ws_size >= ws_needed) {
        h2_prep<<<NEVT, 512, 0, stream>>>(x, W1, b1, W2, b2, (uint4*)d_ws);
        dim3 grid(16, NEVT);
        kde_main<<<grid, 1024, 0, stream>>>((const uint4*)d_ws, W3, b3, out);
    } else {
        dim3 grid(16, NEVT);
        kde_fused<<<grid, 1024, 0, stream>>>(x, W1, b1, W2, b2, W3, b3, out);
    }
}

// Round 6
// 45.100 us; speedup vs baseline: 2.1594x; 1.0792x over previous
//
#include <hip/hip_runtime.h>

#define NOUT1 12
#define NOUT2 15
#define NBINS 4000
#define NFEAT 6
#define NT    500
#define NTPAD 512
#define NEVT  64
#define LOG2E 1.4426950408889634f
#define LN2   0.6931471805599453f

typedef __attribute__((ext_vector_type(8))) short bf16x8;
typedef __attribute__((ext_vector_type(4))) float f32x4;
typedef __attribute__((ext_vector_type(2))) float f32x2;

__device__ __forceinline__ float leaky(float s) {
    return s >= 0.0f ? s : 0.01f * s;
}

__device__ __forceinline__ unsigned short f32_to_bf16_rne(float x) {
    unsigned int u = __float_as_uint(x);
    unsigned int r = (u + 0x7fffu + ((u >> 16) & 1u)) >> 16;
    return (unsigned short)r;
}
__device__ __forceinline__ float bf16_to_f32(unsigned short h) {
    return __uint_as_float((unsigned int)h << 16);
}

// d' = d * log2e (scale folded into W3/b3).
// softplus(d)/ln2 = max(d',0) + log2(1 + 2^(-|d'|)); cubic minimax for
// log2(1+u)/u on (0,1], coeffs = old-ln coeffs / ln2, |abs err| ~= 1.2e-3.
// exp2(-|x|) is ONE v_exp_f32 (neg+abs fold into input modifiers).
__device__ __forceinline__ void sp2_acc(f32x2 d, f32x2& acc) {
    f32x2 u;
    u.x = __builtin_amdgcn_exp2f(-__builtin_fabsf(d.x));
    u.y = __builtin_amdgcn_exp2f(-__builtin_fabsf(d.y));
    acc += __builtin_elementwise_max(d, (f32x2)0.0f);
    f32x2 q = __builtin_elementwise_fma(u, (f32x2)0.175167f, (f32x2)(-0.602758f));
    q = __builtin_elementwise_fma(u, q, (f32x2)1.428718f);
    acc = __builtin_elementwise_fma(u, q, acc);
}

// ---- one track's h2 hi/lo bf16 row (16 packed uints) ----
__device__ __forceinline__ void h2_row(
    const float* __restrict__ x, int e, int t,
    const float* __restrict__ W1, const float* __restrict__ b1,
    const float* __restrict__ W2, const float* __restrict__ b2,
    unsigned int packed[16])
{
    float f[NFEAT];
    #pragma unroll
    for (int i = 0; i < NFEAT; ++i)
        f[i] = x[e * NFEAT * NT + i * NT + t];   // x is (E, F, T)

    float h1[NOUT1];
    #pragma unroll
    for (int o = 0; o < NOUT1; ++o) {
        float s = b1[o];
        #pragma unroll
        for (int i = 0; i < NFEAT; ++i)
            s = fmaf(f[i], W1[o * NFEAT + i], s);
        h1[o] = leaky(s);
    }

    unsigned short hi[16], lo[16];
    #pragma unroll
    for (int o = 0; o < NOUT2; ++o) {
        float s = b2[o];
        #pragma unroll
        for (int i = 0; i < NOUT1; ++i)
            s = fmaf(h1[i], W2[o * NOUT1 + i], s);
        float h2 = leaky(s);
        unsigned short hh = f32_to_bf16_rne(h2);
        hi[o] = hh;
        lo[o] = f32_to_bf16_rne(h2 - bf16_to_f32(hh));
    }
    hi[15] = 0; lo[15] = 0;
    #pragma unroll
    for (int j = 0; j < 8; ++j) {
        packed[j]     = (unsigned int)hi[2*j] | ((unsigned int)hi[2*j+1] << 16);
        packed[8 + j] = (unsigned int)lo[2*j] | ((unsigned int)lo[2*j+1] << 16);
    }
}

// ---- Kernel 1: h2 prep -> ws in MFMA-direct order [e][tile32][kg4][col16] ----
__global__ __launch_bounds__(512) void h2_prep(
    const float* __restrict__ x,
    const float* __restrict__ W1, const float* __restrict__ b1,
    const float* __restrict__ W2, const float* __restrict__ b2,
    uint4* __restrict__ ws)
{
    const int e = blockIdx.x;
    const int t = threadIdx.x;
    unsigned int packed[16];
    if (t < NT) {
        h2_row(x, e, t, W1, b1, W2, b2, packed);
    } else {
        #pragma unroll
        for (int j = 0; j < 16; ++j) packed[j] = 0;
    }
    uint4* dst = ws + (size_t)e * 2048 + (t >> 4) * 64 + (t & 15);
    #pragma unroll
    for (int g = 0; g < 4; ++g)
        dst[g * 16] = make_uint4(packed[4*g+0], packed[4*g+1], packed[4*g+2], packed[4*g+3]);
}

// ---- Phase 2 body: 16 bins x 512 tracks per wave via MFMA ----
__device__ __forceinline__ void kde_phase2(
    const uint4* __restrict__ h2lds,   // [tile32][kg4][col16]
    const float* __restrict__ W3, const float* __restrict__ b3,
    float* __restrict__ out, int chunk, int e, int tid)
{
    const int wid  = tid >> 6;
    const int lane = tid & 63;
    const int col  = lane & 15;
    const int kg   = lane >> 4;
    const int binbase = chunk * 256 + wid * 16;
    if (binbase >= NBINS) return;              // wave-uniform
    const int  bin = binbase + col;
    const bool vb  = (bin < NBINS);

    // B frags (weights pre-scaled by log2e): B1 = [w_hi | w_lo], B2 swapped
    bf16x8 B1, B2;
    const bool hi_first = (kg < 2);
    #pragma unroll
    for (int j = 0; j < 8; ++j) {
        const int kk = (kg * 8 + j) & 15;
        float w = (vb && kk < NOUT2) ? W3[bin * NOUT2 + kk] * LOG2E : 0.0f;
        unsigned short h = f32_to_bf16_rne(w);
        unsigned short l = f32_to_bf16_rne(w - bf16_to_f32(h));
        B1[j] = (short)(hi_first ? h : l);
        B2[j] = (short)(hi_first ? l : h);
    }

    const float bias = vb ? b3[bin] * LOG2E : 0.0f;
    f32x4 bias4 = {bias, bias, bias, bias};

    f32x2 acc01 = {0.0f, 0.0f}, acc23 = {0.0f, 0.0f};
    const bf16x8* ap = reinterpret_cast<const bf16x8*>(h2lds + kg * 16 + col);

    #define TILE_BODY(areg)                                                        \
        {                                                                          \
            f32x4 acc = __builtin_amdgcn_mfma_f32_16x16x32_bf16(areg, B1, bias4, 0, 0, 0); \
            acc = __builtin_amdgcn_mfma_f32_16x16x32_bf16(areg, B2, acc, 0, 0, 0); \
            f32x2 p01 = {acc[0], acc[1]};                                          \
            f32x2 p23 = {acc[2], acc[3]};                                          \
            sp2_acc(p01, acc01);                                                   \
            sp2_acc(p23, acc23);                                                   \
        }

    // prefetch distance 2; tiles 0..30 full, tile 31 masked (tracks 500..511 pad)
    bf16x8 a0 = ap[0 * 64];
    bf16x8 a1 = ap[1 * 64];
    #pragma unroll
    for (int g = 0; g < 15; ++g) {
        bf16x8 n0 = ap[(2 * g + 2) * 64];
        bf16x8 n1 = ap[(2 * g + 3) * 64];
        TILE_BODY(a0)
        TILE_BODY(a1)
        a0 = n0; a1 = n1;
    }
    TILE_BODY(a0)   // tile 30
    {               // tile 31: only kg==0 rows (tracks 496..499) are real
        f32x4 acc = __builtin_amdgcn_mfma_f32_16x16x32_bf16(a1, B1, bias4, 0, 0, 0);
        acc = __builtin_amdgcn_mfma_f32_16x16x32_bf16(a1, B2, acc, 0, 0, 0);
        if (kg == 0) {
            f32x2 p01 = {acc[0], acc[1]};
            f32x2 p23 = {acc[2], acc[3]};
            sp2_acc(p01, acc01);
            sp2_acc(p23, acc23);
        }
    }
    #undef TILE_BODY

    float sum = acc01.x + acc01.y + acc23.x + acc23.y;
    sum += __shfl_xor(sum, 16);
    sum += __shfl_xor(sum, 32);
    if (lane < 16 && vb)
        out[e * NBINS + bin] = sum * LN2;      // undo log2 scaling once
}

// ---- Kernel 2: stage ws -> LDS (identity copy), then MFMA + softplus ----
__global__ __launch_bounds__(1024, 8) void kde_main(
    const uint4* __restrict__ ws,
    const float* __restrict__ W3, const float* __restrict__ b3,
    float* __restrict__ out)
{
    __shared__ uint4 h2lds[2048];   // 32 KB, [tile32][kg4][col16]
    const int tid   = threadIdx.x;
    const int chunk = blockIdx.x;
    const int e     = blockIdx.y;

    h2lds[tid]        = ws[(size_t)e * 2048 + tid];
    h2lds[tid + 1024] = ws[(size_t)e * 2048 + tid + 1024];
    __syncthreads();

    kde_phase2(h2lds, W3, b3, out, chunk, e, tid);
}

// ---- Fallback: fused single kernel (if ws too small) ----
__global__ __launch_bounds__(1024, 2) void kde_fused(
    const float* __restrict__ x,
    const float* __restrict__ W1, const float* __restrict__ b1,
    const float* __restrict__ W2, const float* __restrict__ b2,
    const float* __restrict__ W3, const float* __restrict__ b3,
    float* __restrict__ out)
{
    __shared__ uint4 h2lds[2048];
    const int tid   = threadIdx.x;
    const int chunk = blockIdx.x;
    const int e     = blockIdx.y;

    if (tid < NTPAD) {
        unsigned int packed[16];
        if (tid < NT) {
            h2_row(x, e, tid, W1, b1, W2, b2, packed);
        } else {
            #pragma unroll
            for (int j = 0; j < 16; ++j) packed[j] = 0;
        }
        uint4* dst = &h2lds[(tid >> 4) * 64 + (tid & 15)];
        #pragma unroll
        for (int g = 0; g < 4; ++g)
            dst[g * 16] = make_uint4(packed[4*g+0], packed[4*g+1], packed[4*g+2], packed[4*g+3]);
    }
    __syncthreads();

    kde_phase2(h2lds, W3, b3, out, chunk, e, tid);
}

extern "C" void kernel_launch(void* const* d_in, const int* in_sizes, int n_in,
                              void* d_out, int out_size, void* d_ws, size_t ws_size,
                              hipStream_t stream) {
    const float* x  = (const float*)d_in[0];
    const float* W1 = (const float*)d_in[1];
    const float* b1 = (const float*)d_in[2];
    const float* W2 = (const float*)d_in[3];
    const float* b2 = (const float*)d_in[4];
    const float* W3 = (const float*)d_in[5];
    const float* b3 = (const float*)d_in[6];
    float* out = (float*)d_out;

    const size_t ws_needed = (size_t)NEVT * 2048 * sizeof(uint4);   // 2 MB
    if (ws_size >= ws_needed) {
        h2_prep<<<NEVT, 512, 0, stream>>>(x, W1, b1, W2, b2, (uint4*)d_ws);
        dim3 grid(16, NEVT);
        kde_main<<<grid, 1024, 0, stream>>>((const uint4*)d_ws, W3, b3, out);
    } else {
        dim3 grid(16, NEVT);
        kde_fused<<<grid, 1024, 0, stream>>>(x, W1, b1, W2, b2, W3, b3, out);
    }
}

// Round 7
// 44.595 us; speedup vs baseline: 2.1838x; 1.0113x over previous
//
#include <hip/hip_runtime.h>

#define NOUT1 12
#define NOUT2 15
#define NBINS 4000
#define NFEAT 6
#define NT    500
#define NTPAD 512
#define NEVT  64
#define LOG2E 1.4426950408889634f
#define LN2   0.6931471805599453f

typedef __attribute__((ext_vector_type(8))) short bf16x8;
typedef __attribute__((ext_vector_type(4))) float f32x4;
typedef __attribute__((ext_vector_type(2))) float f32x2;

__device__ __forceinline__ float leaky(float s) {
    return s >= 0.0f ? s : 0.01f * s;
}

__device__ __forceinline__ unsigned short f32_to_bf16_rne(float x) {
    unsigned int u = __float_as_uint(x);
    unsigned int r = (u + 0x7fffu + ((u >> 16) & 1u)) >> 16;
    return (unsigned short)r;
}
__device__ __forceinline__ float bf16_to_f32(unsigned short h) {
    return __uint_as_float((unsigned int)h << 16);
}

// d' = d * log2e (scale folded into W3/b3).
// softplus(d)/ln2 = max(d',0) + log2(1 + 2^(-|d'|)); cubic minimax,
// |abs err| ~= 1.2e-3 (in ln units). exp2(-|x|) is ONE v_exp_f32.
__device__ __forceinline__ void sp2_acc(f32x2 d, f32x2& acc) {
    f32x2 u;
    u.x = __builtin_amdgcn_exp2f(-__builtin_fabsf(d.x));
    u.y = __builtin_amdgcn_exp2f(-__builtin_fabsf(d.y));
    acc += __builtin_elementwise_max(d, (f32x2)0.0f);
    f32x2 q = __builtin_elementwise_fma(u, (f32x2)0.175167f, (f32x2)(-0.602758f));
    q = __builtin_elementwise_fma(u, q, (f32x2)1.428718f);
    acc = __builtin_elementwise_fma(u, q, acc);
}

// ---- one track's h2 hi/lo bf16 row (16 packed uints) ----
__device__ __forceinline__ void h2_row(
    const float* __restrict__ x, int e, int t,
    const float* __restrict__ W1, const float* __restrict__ b1,
    const float* __restrict__ W2, const float* __restrict__ b2,
    unsigned int packed[16])
{
    float f[NFEAT];
    #pragma unroll
    for (int i = 0; i < NFEAT; ++i)
        f[i] = x[e * NFEAT * NT + i * NT + t];   // x is (E, F, T)

    float h1[NOUT1];
    #pragma unroll
    for (int o = 0; o < NOUT1; ++o) {
        float s = b1[o];
        #pragma unroll
        for (int i = 0; i < NFEAT; ++i)
            s = fmaf(f[i], W1[o * NFEAT + i], s);
        h1[o] = leaky(s);
    }

    unsigned short hi[16], lo[16];
    #pragma unroll
    for (int o = 0; o < NOUT2; ++o) {
        float s = b2[o];
        #pragma unroll
        for (int i = 0; i < NOUT1; ++i)
            s = fmaf(h1[i], W2[o * NOUT1 + i], s);
        float h2 = leaky(s);
        unsigned short hh = f32_to_bf16_rne(h2);
        hi[o] = hh;
        lo[o] = f32_to_bf16_rne(h2 - bf16_to_f32(hh));
    }
    hi[15] = 0; lo[15] = 0;
    #pragma unroll
    for (int j = 0; j < 8; ++j) {
        packed[j]     = (unsigned int)hi[2*j] | ((unsigned int)hi[2*j+1] << 16);
        packed[8 + j] = (unsigned int)lo[2*j] | ((unsigned int)lo[2*j+1] << 16);
    }
}

// ---- Kernel 1: h2 prep -> ws in MFMA-direct order [e][tile32][kg4][col16] ----
__global__ __launch_bounds__(256) void h2_prep(
    const float* __restrict__ x,
    const float* __restrict__ W1, const float* __restrict__ b1,
    const float* __restrict__ W2, const float* __restrict__ b2,
    uint4* __restrict__ ws)
{
    const int e = blockIdx.x;
    const int t = blockIdx.y * 256 + threadIdx.x;
    unsigned int packed[16];
    if (t < NT) {
        h2_row(x, e, t, W1, b1, W2, b2, packed);
    } else {
        #pragma unroll
        for (int j = 0; j < 16; ++j) packed[j] = 0;
    }
    uint4* dst = ws + (size_t)e * 2048 + (t >> 4) * 64 + (t & 15);
    #pragma unroll
    for (int g = 0; g < 4; ++g)
        dst[g * 16] = make_uint4(packed[4*g+0], packed[4*g+1], packed[4*g+2], packed[4*g+3]);
}

// ---- Phase 2 body: 16 bins x 512 tracks per wave via MFMA ----
__device__ __forceinline__ void kde_phase2(
    const uint4* __restrict__ h2lds,   // [tile32][kg4][col16]
    const float* __restrict__ W3, const float* __restrict__ b3,
    float* __restrict__ out, int chunk, int e, int tid)
{
    const int wid  = tid >> 6;
    const int lane = tid & 63;
    const int col  = lane & 15;
    const int kg   = lane >> 4;
    const int binbase = chunk * 256 + wid * 16;
    if (binbase >= NBINS) return;              // wave-uniform
    const int  bin = binbase + col;
    const bool vb  = (bin < NBINS);

    // B frags (weights pre-scaled by log2e): B1 = [w_hi | w_lo], B2 swapped
    bf16x8 B1, B2;
    const bool hi_first = (kg < 2);
    #pragma unroll
    for (int j = 0; j < 8; ++j) {
        const int kk = (kg * 8 + j) & 15;
        float w = (vb && kk < NOUT2) ? W3[bin * NOUT2 + kk] * LOG2E : 0.0f;
        unsigned short h = f32_to_bf16_rne(w);
        unsigned short l = f32_to_bf16_rne(w - bf16_to_f32(h));
        B1[j] = (short)(hi_first ? h : l);
        B2[j] = (short)(hi_first ? l : h);
    }

    const float bias = vb ? b3[bin] * LOG2E : 0.0f;
    f32x4 bias4 = {bias, bias, bias, bias};

    f32x2 acc01 = {0.0f, 0.0f}, acc23 = {0.0f, 0.0f};
    const bf16x8* ap = reinterpret_cast<const bf16x8*>(h2lds + kg * 16 + col);

    #define TILE_BODY(areg)                                                        \
        {                                                                          \
            f32x4 acc = __builtin_amdgcn_mfma_f32_16x16x32_bf16(areg, B1, bias4, 0, 0, 0); \
            acc = __builtin_amdgcn_mfma_f32_16x16x32_bf16(areg, B2, acc, 0, 0, 0); \
            f32x2 p01 = {acc[0], acc[1]};                                          \
            f32x2 p23 = {acc[2], acc[3]};                                          \
            sp2_acc(p01, acc01);                                                   \
            sp2_acc(p23, acc23);                                                   \
        }

    // distance-4 LDS prefetch ring; full unroll keeps all indices static
    bf16x8 A[4];
    A[0] = ap[0 * 64];
    A[1] = ap[1 * 64];
    A[2] = ap[2 * 64];
    A[3] = ap[3 * 64];

    #pragma unroll
    for (int g = 0; g < 31; ++g) {
        bf16x8 cur = A[g & 3];
        if (g + 4 < 32)
            A[g & 3] = ap[(g + 4) * 64];   // issue next ds_read before compute
        TILE_BODY(cur)
    }
    {   // tile 31: tracks 496..511; only kg==0 rows (tracks 496..499) are real
        bf16x8 cur = A[31 & 3];
        f32x4 acc = __builtin_amdgcn_mfma_f32_16x16x32_bf16(cur, B1, bias4, 0, 0, 0);
        acc = __builtin_amdgcn_mfma_f32_16x16x32_bf16(cur, B2, acc, 0, 0, 0);
        if (kg == 0) {
            f32x2 p01 = {acc[0], acc[1]};
            f32x2 p23 = {acc[2], acc[3]};
            sp2_acc(p01, acc01);
            sp2_acc(p23, acc23);
        }
    }
    #undef TILE_BODY

    float sum = acc01.x + acc01.y + acc23.x + acc23.y;
    sum += __shfl_xor(sum, 16);
    sum += __shfl_xor(sum, 32);
    if (lane < 16 && vb)
        out[e * NBINS + bin] = sum * LN2;      // undo log2 scaling once
}

// ---- Kernel 2: stage ws -> LDS (identity copy), then MFMA + softplus ----
__global__ __launch_bounds__(1024, 4) void kde_main(
    const uint4* __restrict__ ws,
    const float* __restrict__ W3, const float* __restrict__ b3,
    float* __restrict__ out)
{
    __shared__ uint4 h2lds[2048];   // 32 KB, [tile32][kg4][col16]
    const int tid   = threadIdx.x;
    const int chunk = blockIdx.x;
    const int e     = blockIdx.y;

    h2lds[tid]        = ws[(size_t)e * 2048 + tid];
    h2lds[tid + 1024] = ws[(size_t)e * 2048 + tid + 1024];
    __syncthreads();

    kde_phase2(h2lds, W3, b3, out, chunk, e, tid);
}

// ---- Fallback: fused single kernel (if ws too small) ----
__global__ __launch_bounds__(1024, 2) void kde_fused(
    const float* __restrict__ x,
    const float* __restrict__ W1, const float* __restrict__ b1,
    const float* __restrict__ W2, const float* __restrict__ b2,
    const float* __restrict__ W3, const float* __restrict__ b3,
    float* __restrict__ out)
{
    __shared__ uint4 h2lds[2048];
    const int tid   = threadIdx.x;
    const int chunk = blockIdx.x;
    const int e     = blockIdx.y;

    if (tid < NTPAD) {
        unsigned int packed[16];
        if (tid < NT) {
            h2_row(x, e, tid, W1, b1, W2, b2, packed);
        } else {
            #pragma unroll
            for (int j = 0; j < 16; ++j) packed[j] = 0;
        }
        uint4* dst = &h2lds[(tid >> 4) * 64 + (tid & 15)];
        #pragma unroll
        for (int g = 0; g < 4; ++g)
            dst[g * 16] = make_uint4(packed[4*g+0], packed[4*g+1], packed[4*g+2], packed[4*g+3]);
    }
    __syncthreads();

    kde_phase2(h2lds, W3, b3, out, chunk, e, tid);
}

extern "C" void kernel_launch(void* const* d_in, const int* in_sizes, int n_in,
                              void* d_out, int out_size, void* d_ws, size_t ws_size,
                              hipStream_t stream) {
    const float* x  = (const float*)d_in[0];
    const float* W1 = (const float*)d_in[1];
    const float* b1 = (const float*)d_in[2];
    const float* W2 = (const float*)d_in[3];
    const float* b2 = (const float*)d_in[4];
    const float* W3 = (const float*)d_in[5];
    const float* b3 = (const float*)d_in[6];
    float* out = (float*)d_out;

    const size_t ws_needed = (size_t)NEVT * 2048 * sizeof(uint4);   // 2 MB
    if (ws_size >= ws_needed) {
        dim3 pgrid(NEVT, 2);
        h2_prep<<<pgrid, 256, 0, stream>>>(x, W1, b1, W2, b2, (uint4*)d_ws);
        dim3 grid(16, NEVT);
        kde_main<<<grid, 1024, 0, stream>>>((const uint4*)d_ws, W3, b3, out);
    } else {
        dim3 grid(16, NEVT);
        kde_fused<<<grid, 1024, 0, stream>>>(x, W1, b1, W2, b2, W3, b3, out);
    }
}